// Round 17
// baseline (208.474 us; speedup 1.0000x reference)
//
#include <hip/hip_runtime.h>
#include <stdint.h>

#define BATCH 16384
#define SDIM 512
#define ADIM 64
#define XDIM 576      // SDIM + ADIM
#define HDIM 1024
#define NQD 64
#define QED 64

typedef __attribute__((ext_vector_type(8))) short short8;
typedef __attribute__((ext_vector_type(4))) float f32x4;

static __device__ inline unsigned short f2bf(float f) {
  unsigned int u = __float_as_uint(f);
  unsigned int r = (u + 0x7fffu + ((u >> 16) & 1u)) >> 16;
  return (unsigned short)r;
}
static __device__ inline float bf2f(unsigned short u) {
  return __uint_as_float(((unsigned int)u) << 16);
}

static __device__ inline void gload_lds16(const void* g, void* l) {
  __builtin_amdgcn_global_load_lds(
      (const __attribute__((address_space(1))) uint32_t*)g,
      (__attribute__((address_space(3))) uint32_t*)l, 16, 0, 0);
}

// ---------------- merged conversion + tau kernel ----------------
// blocks 0..2047: x concat + W_f1/W_f2 bf16 conversion (grid-stride)
// blocks 2048..2079: tau-embedding head contribution (4 units/block)

__global__ __launch_bounds__(256) void prep_all(const float* __restrict__ st,
                                                const float* __restrict__ ac,
                                                unsigned short* __restrict__ xb,
                                                const float* __restrict__ w1s,
                                                unsigned short* __restrict__ w1d,
                                                const float* __restrict__ w2s,
                                                unsigned short* __restrict__ w2d,
                                                const float* __restrict__ We1,
                                                const float* __restrict__ be1,
                                                const float* __restrict__ We2,
                                                const float* __restrict__ be2,
                                                const float* __restrict__ Wh,
                                                const float* __restrict__ bh,
                                                float* __restrict__ qtau) {
  const int bid = (int)blockIdx.x;
  if (bid >= 2048) {
    // ---- qtau part: exact fp32, one wave per (c, nq) unit ----
    const int u = (bid - 2048) * 4 + ((int)threadIdx.x >> 6);  // 0..127
    const int c = u >> 6;
    const int nq = u & 63;
    const int q = (int)threadIdx.x & 63;
    const float tau = (float)nq / 64.0f + 0.0078125f;
    float acc = be2[c * 64 + q];
    for (int e = 0; e < 64; ++e) {
      const float t1 = fmaxf(tau * We1[c * 64 + e] + be1[c * 64 + e], 0.0f);
      acc += t1 * We2[(c * 64 + q) * 64 + e];
    }
    float v = acc * Wh[c * (HDIM + QED) + HDIM + q];
    #pragma unroll
    for (int off = 32; off; off >>= 1) v += __shfl_xor(v, off);
    if (q == 0) qtau[c * 64 + nq] = v + bh[c];
    return;
  }
  const int nx = BATCH * XDIM / 4;
  const int n1 = 2 * HDIM * XDIM / 4;
  const int n2 = 2 * HDIM * HDIM / 4;
  for (int i = bid * 256 + (int)threadIdx.x; i < nx + n1 + n2; i += 2048 * 256) {
    float4 v;
    unsigned short* dst;
    int di;
    if (i < nx) {
      const int e = i * 4;
      const int b = e / XDIM;
      const int j = e - b * XDIM;
      if (j < SDIM) v = *(const float4*)(st + (size_t)b * SDIM + j);
      else          v = *(const float4*)(ac + (size_t)b * ADIM + (j - SDIM));
      dst = xb; di = i;
    } else if (i < nx + n1) {
      di = i - nx; v = ((const float4*)w1s)[di]; dst = w1d;
    } else {
      di = i - nx - n1; v = ((const float4*)w2s)[di]; dst = w2d;
    }
    ushort4 o;
    o.x = f2bf(v.x); o.y = f2bf(v.y); o.z = f2bf(v.z); o.w = f2bf(v.w);
    ((ushort4*)dst)[di] = o;
  }
}

// ---------------- critic-batched 128x128 bf16 GEMM, 4 blocks/CU ------------
// Both critics in ONE dispatch (grid 2048 = 8 XCD x 256 jobs).
// C[c][M,1024] = A[c] * W[c]^T + b[c].
// Core = R6 (proven 128² 4-wave, 56 VGPR) + R8 slot swizzle + R12 packed
// epilogue (plain stores — NT reverted, R16 falsified the RMW theory).
// 32 KiB LDS + __launch_bounds__(256,4) -> 4 blocks/CU resident ->
// 2048 jobs / 1024 slots = exactly 2 residency rounds (was 2 rounds of the
// 2x-bigger 256x128 tile at 3 blocks/CU = same rounds, double T_block).
// Job map: XCD x = bid&7, r = bid>>3: n = r&7, c = (r>>3)&1, m = x*16+(r>>4)
// -> the 16 blocks (8n x 2c) sharing an A-panel are XCD-co-resident.
// NOTE: A and C must NOT alias (in-dispatch cross-block RW race otherwise).

template <int K>
__global__ __launch_bounds__(256, 4) void gemm_bc(const unsigned short* __restrict__ Abase,
                                                  size_t aCritStride,
                                                  const unsigned short* __restrict__ Wbase,
                                                  const float* __restrict__ biasBase,
                                                  unsigned short* __restrict__ Cbase) {
  constexpr int NT = K / 32;
  __shared__ unsigned short As[2][128][32];  // 16 KiB
  __shared__ unsigned short Bs[2][128][32];  // 16 KiB  (32 KiB pool, reused by epilogue)

  const int tid  = threadIdx.x;
  const int lane = tid & 63;
  const int wave = tid >> 6;
  const int wm = wave >> 1;   // 0..1 -> rows [wm*64, wm*64+64)
  const int wn = wave & 1;    // 0..1 -> cols [wn*64, wn*64+64)

  const int bid = (int)blockIdx.x;
  const int x = bid & 7;            // XCD
  const int r = bid >> 3;           // 0..255 within XCD
  const int n = r & 7;
  const int cidx = (r >> 3) & 1;
  const int m = x * 16 + (r >> 4);  // 0..127
  const int mBase = m * 128;
  const int nBase = n * 128;

  const unsigned short* A = Abase + aCritStride * (size_t)cidx;
  const unsigned short* W = Wbase + (size_t)cidx * HDIM * K;
  const float* bias = biasBase + cidx * HDIM;
  unsigned short* C = Cbase + (size_t)cidx * BATCH * HDIM;

  auto stage = [&](int buf, int kt) {
    #pragma unroll
    for (int i = 0; i < 2; ++i) {
      const int flat = i * 256 + tid;      // 0..511
      const int row  = flat >> 2;          // 0..127
      const int ls   = (flat & 3) ^ ((row >> 1) & 3);
      gload_lds16(A + (size_t)(mBase + row) * K + kt * 32 + ls * 8,
                  &As[buf][0][0] + (size_t)flat * 8);
      gload_lds16(W + (size_t)(nBase + row) * K + kt * 32 + ls * 8,
                  &Bs[buf][0][0] + (size_t)flat * 8);
    }
  };

  f32x4 acc[4][4];
  #pragma unroll
  for (int fm = 0; fm < 4; ++fm)
    #pragma unroll
    for (int fn = 0; fn < 4; ++fn) {
      f32x4 z = {0.f, 0.f, 0.f, 0.f};
      acc[fm][fn] = z;
    }

  stage(0, 0);
  __syncthreads();

  for (int t = 0; t < NT; ++t) {
    const int buf = t & 1;
    if (t + 1 < NT) stage(buf ^ 1, t + 1);

    short8 af[4], bf[4];
    #pragma unroll
    for (int fm = 0; fm < 4; ++fm) {
      const int rr = wm * 64 + fm * 16 + (lane & 15);
      const int ps = (lane >> 4) ^ ((rr >> 1) & 3);
      af[fm] = *(const short8*)&As[buf][rr][ps * 8];
    }
    #pragma unroll
    for (int fn = 0; fn < 4; ++fn) {
      const int rr = wn * 64 + fn * 16 + (lane & 15);
      const int ps = (lane >> 4) ^ ((rr >> 1) & 3);
      bf[fn] = *(const short8*)&Bs[buf][rr][ps * 8];
    }

    __builtin_amdgcn_s_setprio(1);
    #pragma unroll
    for (int fm = 0; fm < 4; ++fm)
      #pragma unroll
      for (int fn = 0; fn < 4; ++fn)
        acc[fm][fn] = __builtin_amdgcn_mfma_f32_16x16x32_bf16(af[fm], bf[fn],
                                                              acc[fm][fn], 0, 0, 0);
    __builtin_amdgcn_s_setprio(0);
    __syncthreads();
  }

  // ---- packed epilogue: LDS transpose -> full-128B-line dwordx4 stores ----
  __syncthreads();  // all waves done reading As/Bs before patch overwrite
  unsigned short* patch = ((unsigned short*)&As[0][0][0]) + wave * 2304;  // 32x72 shorts, 4 waves = 18 KiB

  float bcol[4];
  #pragma unroll
  for (int fn = 0; fn < 4; ++fn)
    bcol[fn] = bias[nBase + wn * 64 + fn * 16 + (lane & 15)];

  const int cBase = nBase + wn * 64;

  #pragma unroll
  for (int p = 0; p < 2; ++p) {
    #pragma unroll
    for (int f2 = 0; f2 < 2; ++f2) {
      const int fm = p * 2 + f2;
      #pragma unroll
      for (int fn = 0; fn < 4; ++fn) {
        const int rl = f2 * 16 + (lane >> 4) * 4;
        const int cl = fn * 16 + (lane & 15);
        #pragma unroll
        for (int j = 0; j < 4; ++j)
          patch[(rl + j) * 72 + cl] = f2bf(acc[fm][fn][j] + bcol[fn]);
      }
    }
    #pragma unroll
    for (int k = 0; k < 4; ++k) {
      const int rl = k * 8 + (lane >> 3);
      const short8 v = *(const short8*)&patch[rl * 72 + (lane & 7) * 8];
      const int rowg = mBase + wm * 64 + p * 32 + rl;
      *(short8*)(C + (size_t)rowg * HDIM + cBase + (lane & 7) * 8) = v;
    }
  }
}

// ---------------- critic-batched LayerNorm + ReLU (+ head) -----------------

template <bool HEAD>
__global__ __launch_bounds__(256) void ln_bc(const unsigned short* __restrict__ Xb,
                                             const float* __restrict__ gB,
                                             const float* __restrict__ btB,
                                             unsigned short* __restrict__ Yb,
                                             const float* __restrict__ WhB,
                                             const float* __restrict__ qtB,
                                             float* __restrict__ outB) {
  const int gb = blockIdx.x;
  const int c = gb >> 14;                 // BATCH = 2^14
  const int row = gb & (BATCH - 1);
  const unsigned short* X = Xb + ((size_t)c * BATCH + row) * HDIM;
  const float* g   = gB + c * HDIM;
  const float* bta = btB + c * HDIM;

  const int tid = threadIdx.x;
  const int lane = tid & 63;
  const int wave = tid >> 6;
  __shared__ float rs_[4], rq_[4], rp_[4];

  const ushort4 xv = ((const ushort4*)X)[tid];
  const float x0 = bf2f(xv.x), x1 = bf2f(xv.y), x2 = bf2f(xv.z), x3 = bf2f(xv.w);
  float s = x0 + x1 + x2 + x3;
  float q = x0 * x0 + x1 * x1 + x2 * x2 + x3 * x3;
  #pragma unroll
  for (int off = 32; off; off >>= 1) {
    s += __shfl_xor(s, off);
    q += __shfl_xor(q, off);
  }
  if (lane == 0) { rs_[wave] = s; rq_[wave] = q; }
  __syncthreads();
  s = rs_[0] + rs_[1] + rs_[2] + rs_[3];
  q = rq_[0] + rq_[1] + rq_[2] + rq_[3];
  const float mu = s * (1.0f / 1024.0f);
  const float var = q * (1.0f / 1024.0f) - mu * mu;
  const float rsig = rsqrtf(var + 1e-5f);

  const float4 gv = ((const float4*)g)[tid];
  const float4 bv = ((const float4*)bta)[tid];
  const float y0 = fmaxf((x0 - mu) * rsig * gv.x + bv.x, 0.0f);
  const float y1 = fmaxf((x1 - mu) * rsig * gv.y + bv.y, 0.0f);
  const float y2 = fmaxf((x2 - mu) * rsig * gv.z + bv.z, 0.0f);
  const float y3 = fmaxf((x3 - mu) * rsig * gv.w + bv.w, 0.0f);

  if constexpr (!HEAD) {
    ushort4 o;
    o.x = f2bf(y0); o.y = f2bf(y1); o.z = f2bf(y2); o.w = f2bf(y3);
    ((ushort4*)(Yb + ((size_t)c * BATCH + row) * HDIM))[tid] = o;
  } else {
    const float* Wh = WhB + c * (HDIM + QED);
    const float4 wv = ((const float4*)Wh)[tid];
    float p = y0 * wv.x + y1 * wv.y + y2 * wv.z + y3 * wv.w;
    #pragma unroll
    for (int off = 32; off; off >>= 1) p += __shfl_xor(p, off);
    if (lane == 0) rp_[wave] = p;
    __syncthreads();
    if (tid < 64) {
      const float qf = rp_[0] + rp_[1] + rp_[2] + rp_[3];
      outB[((size_t)c * BATCH + row) * NQD + tid] = qf + qtB[c * 64 + tid];
    }
  }
}

// ---------------- launch ----------------

extern "C" void kernel_launch(void* const* d_in, const int* in_sizes, int n_in,
                              void* d_out, int out_size, void* d_ws, size_t ws_size,
                              hipStream_t stream) {
  (void)in_sizes; (void)n_in; (void)out_size; (void)ws_size;
  const float* state  = (const float*)d_in[0];
  const float* action = (const float*)d_in[1];
  const float* We1 = (const float*)d_in[2];
  const float* be1 = (const float*)d_in[3];
  const float* We2 = (const float*)d_in[4];
  const float* be2 = (const float*)d_in[5];
  const float* Wf1 = (const float*)d_in[6];
  const float* bW1 = (const float*)d_in[7];
  const float* g1  = (const float*)d_in[8];
  const float* bt1 = (const float*)d_in[9];
  const float* Wf2 = (const float*)d_in[10];
  const float* bW2 = (const float*)d_in[11];
  const float* g2  = (const float*)d_in[12];
  const float* bt2 = (const float*)d_in[13];
  const float* Wh  = (const float*)d_in[14];
  const float* bh  = (const float*)d_in[15];
  float* out = (float*)d_out;

  char* ws = (char*)d_ws;
  unsigned short* xb   = (unsigned short*)(ws);               // BATCH*576 bf16   (18,874,368 B)
  unsigned short* w1b  = (unsigned short*)(ws + 18874368);    // 2*1024*576 bf16  (2,359,296 B)
  unsigned short* w2b  = (unsigned short*)(ws + 21233664);    // 2*1024*1024 bf16 (4,194,304 B)
  float*          qtw  = (float*)(ws + 25427968);             // 2*64 f32 (512 B)
  unsigned short* ha   = (unsigned short*)(ws + 25428480);    // 2*BATCH*1024 bf16 -> ends 92,537,344
  unsigned short* hb   = (unsigned short*)(ws + 92537344);    // 2*BATCH*1024 bf16 -> ends 159,646,208

  prep_all<<<2080, 256, 0, stream>>>(state, action, xb, Wf1, w1b, Wf2, w2b,
                                     We1, be1, We2, be2, Wh, bh, qtw);

  // layer 1, both critics (A shared across critics): ha = x @ W1^T + b1
  gemm_bc<XDIM><<<2048, 256, 0, stream>>>(xb, 0, w1b, bW1, ha);
  ln_bc<false><<<2 * BATCH, 256, 0, stream>>>(ha, g1, bt1, hb, nullptr, nullptr, nullptr);
  // layer 2, both critics: ha = hb @ W2^T + b2 ; then LN+head -> out
  gemm_bc<HDIM><<<2048, 256, 0, stream>>>(hb, (size_t)BATCH * HDIM, w2b, bW2, ha);
  ln_bc<true><<<2 * BATCH, 256, 0, stream>>>(ha, g2, bt2, nullptr, Wh, qtw, out);
}

// Round 18
// 196.243 us; speedup vs baseline: 1.0623x; 1.0623x over previous
//
#include <hip/hip_runtime.h>
#include <stdint.h>

#define BATCH 16384
#define SDIM 512
#define ADIM 64
#define XDIM 576      // SDIM + ADIM
#define HDIM 1024
#define NQD 64
#define QED 64

typedef __attribute__((ext_vector_type(8))) short short8;
typedef __attribute__((ext_vector_type(4))) float f32x4;

static __device__ inline unsigned short f2bf(float f) {
  unsigned int u = __float_as_uint(f);
  unsigned int r = (u + 0x7fffu + ((u >> 16) & 1u)) >> 16;
  return (unsigned short)r;
}
static __device__ inline float bf2f(unsigned short u) {
  return __uint_as_float(((unsigned int)u) << 16);
}

static __device__ inline void gload_lds16(const void* g, void* l) {
  __builtin_amdgcn_global_load_lds(
      (const __attribute__((address_space(1))) uint32_t*)g,
      (__attribute__((address_space(3))) uint32_t*)l, 16, 0, 0);
}

// ---------------- merged conversion + tau kernel ----------------
// blocks 0..2047: x concat + W_f1/W_f2 bf16 conversion (grid-stride)
// blocks 2048..2079: tau-embedding head contribution (4 units/block)

__global__ __launch_bounds__(256) void prep_all(const float* __restrict__ st,
                                                const float* __restrict__ ac,
                                                unsigned short* __restrict__ xb,
                                                const float* __restrict__ w1s,
                                                unsigned short* __restrict__ w1d,
                                                const float* __restrict__ w2s,
                                                unsigned short* __restrict__ w2d,
                                                const float* __restrict__ We1,
                                                const float* __restrict__ be1,
                                                const float* __restrict__ We2,
                                                const float* __restrict__ be2,
                                                const float* __restrict__ Wh,
                                                const float* __restrict__ bh,
                                                float* __restrict__ qtau) {
  const int bid = (int)blockIdx.x;
  if (bid >= 2048) {
    // ---- qtau part: exact fp32, one wave per (c, nq) unit ----
    const int u = (bid - 2048) * 4 + ((int)threadIdx.x >> 6);  // 0..127
    const int c = u >> 6;
    const int nq = u & 63;
    const int q = (int)threadIdx.x & 63;
    const float tau = (float)nq / 64.0f + 0.0078125f;
    float acc = be2[c * 64 + q];
    for (int e = 0; e < 64; ++e) {
      const float t1 = fmaxf(tau * We1[c * 64 + e] + be1[c * 64 + e], 0.0f);
      acc += t1 * We2[(c * 64 + q) * 64 + e];
    }
    float v = acc * Wh[c * (HDIM + QED) + HDIM + q];
    #pragma unroll
    for (int off = 32; off; off >>= 1) v += __shfl_xor(v, off);
    if (q == 0) qtau[c * 64 + nq] = v + bh[c];
    return;
  }
  const int nx = BATCH * XDIM / 4;
  const int n1 = 2 * HDIM * XDIM / 4;
  const int n2 = 2 * HDIM * HDIM / 4;
  for (int i = bid * 256 + (int)threadIdx.x; i < nx + n1 + n2; i += 2048 * 256) {
    float4 v;
    unsigned short* dst;
    int di;
    if (i < nx) {
      const int e = i * 4;
      const int b = e / XDIM;
      const int j = e - b * XDIM;
      if (j < SDIM) v = *(const float4*)(st + (size_t)b * SDIM + j);
      else          v = *(const float4*)(ac + (size_t)b * ADIM + (j - SDIM));
      dst = xb; di = i;
    } else if (i < nx + n1) {
      di = i - nx; v = ((const float4*)w1s)[di]; dst = w1d;
    } else {
      di = i - nx - n1; v = ((const float4*)w2s)[di]; dst = w2d;
    }
    ushort4 o;
    o.x = f2bf(v.x); o.y = f2bf(v.y); o.z = f2bf(v.z); o.w = f2bf(v.w);
    ((ushort4*)dst)[di] = o;
  }
}

// ---------------- critic-batched 256x128 bf16 GEMM (R12/R15, proven best) --
// Both critics in ONE dispatch (grid 1024). C[c][M,1024] = A[c] * W[c]^T + b[c].
// 8 waves (4M x 2N), BK=32, 48 KiB LDS dbuf, both-sides slot swizzle,
// packed LDS-transpose epilogue (full-128B-line dwordx4 stores).
// Block mapping keeps the 16 blocks (8n x 2c) sharing an A-panel XCD-co-resident.
// NOTE: A and C must NOT alias (in-dispatch cross-block RW race otherwise).

template <int K>
__global__ __launch_bounds__(512, 4) void gemm_bc(const unsigned short* __restrict__ Abase,
                                                  size_t aCritStride,
                                                  const unsigned short* __restrict__ Wbase,
                                                  const float* __restrict__ biasBase,
                                                  unsigned short* __restrict__ Cbase) {
  constexpr int NT = K / 32;
  __shared__ unsigned short As[2][256][32];  // 32 KiB
  __shared__ unsigned short Bs[2][128][32];  // 16 KiB  (48 KiB pool, reused by epilogue)

  const int tid  = threadIdx.x;
  const int lane = tid & 63;
  const int wave = tid >> 6;
  const int wm = wave >> 1;   // 0..3 -> rows [wm*64, wm*64+64)
  const int wn = wave & 1;    // 0..1 -> cols [wn*64, wn*64+64)

  const int bid = (int)blockIdx.x;
  const int L = (bid & 7) * 128 + (bid >> 3);
  const int n = L & 7;
  const int cidx = (L >> 3) & 1;
  const int m = L >> 4;
  const int mBase = m * 256;
  const int nBase = n * 128;

  const unsigned short* A = Abase + aCritStride * (size_t)cidx;
  const unsigned short* W = Wbase + (size_t)cidx * HDIM * K;
  const float* bias = biasBase + cidx * HDIM;
  unsigned short* C = Cbase + (size_t)cidx * BATCH * HDIM;

  auto stage = [&](int buf, int kt) {
    #pragma unroll
    for (int i = 0; i < 2; ++i) {
      const int flat = i * 512 + tid;
      const int row  = flat >> 2;
      const int ls   = (flat & 3) ^ ((row >> 1) & 3);
      gload_lds16(A + (size_t)(mBase + row) * K + kt * 32 + ls * 8,
                  &As[buf][0][0] + (size_t)flat * 8);
    }
    {
      const int row = tid >> 2;
      const int ls  = (tid & 3) ^ ((row >> 1) & 3);
      gload_lds16(W + (size_t)(nBase + row) * K + kt * 32 + ls * 8,
                  &Bs[buf][0][0] + (size_t)tid * 8);
    }
  };

  f32x4 acc[4][4];
  #pragma unroll
  for (int fm = 0; fm < 4; ++fm)
    #pragma unroll
    for (int fn = 0; fn < 4; ++fn) {
      f32x4 z = {0.f, 0.f, 0.f, 0.f};
      acc[fm][fn] = z;
    }

  stage(0, 0);
  __syncthreads();

  for (int t = 0; t < NT; ++t) {
    const int buf = t & 1;
    if (t + 1 < NT) stage(buf ^ 1, t + 1);

    short8 af[4], bf[4];
    #pragma unroll
    for (int fm = 0; fm < 4; ++fm) {
      const int r  = wm * 64 + fm * 16 + (lane & 15);
      const int ps = (lane >> 4) ^ ((r >> 1) & 3);
      af[fm] = *(const short8*)&As[buf][r][ps * 8];
    }
    #pragma unroll
    for (int fn = 0; fn < 4; ++fn) {
      const int r  = wn * 64 + fn * 16 + (lane & 15);
      const int ps = (lane >> 4) ^ ((r >> 1) & 3);
      bf[fn] = *(const short8*)&Bs[buf][r][ps * 8];
    }

    __builtin_amdgcn_s_setprio(1);
    #pragma unroll
    for (int fm = 0; fm < 4; ++fm)
      #pragma unroll
      for (int fn = 0; fn < 4; ++fn)
        acc[fm][fn] = __builtin_amdgcn_mfma_f32_16x16x32_bf16(af[fm], bf[fn],
                                                              acc[fm][fn], 0, 0, 0);
    __builtin_amdgcn_s_setprio(0);
    __syncthreads();
  }

  // ---- packed epilogue: LDS transpose -> full-128B-line dwordx4 stores ----
  __syncthreads();  // all waves done reading As/Bs before patch overwrite
  unsigned short* patch = ((unsigned short*)&As[0][0][0]) + wave * 2304;  // 32x72 shorts

  float bcol[4];
  #pragma unroll
  for (int fn = 0; fn < 4; ++fn)
    bcol[fn] = bias[nBase + wn * 64 + fn * 16 + (lane & 15)];

  const int cBase = nBase + wn * 64;

  #pragma unroll
  for (int p = 0; p < 2; ++p) {
    #pragma unroll
    for (int f2 = 0; f2 < 2; ++f2) {
      const int fm = p * 2 + f2;
      #pragma unroll
      for (int fn = 0; fn < 4; ++fn) {
        const int rl = f2 * 16 + (lane >> 4) * 4;
        const int cl = fn * 16 + (lane & 15);
        #pragma unroll
        for (int j = 0; j < 4; ++j)
          patch[(rl + j) * 72 + cl] = f2bf(acc[fm][fn][j] + bcol[fn]);
      }
    }
    #pragma unroll
    for (int k = 0; k < 4; ++k) {
      const int rl = k * 8 + (lane >> 3);
      const short8 v = *(const short8*)&patch[rl * 72 + (lane & 7) * 8];
      const int rowg = mBase + wm * 64 + p * 32 + rl;
      *(short8*)(C + (size_t)rowg * HDIM + cBase + (lane & 7) * 8) = v;
    }
  }
}

// ---------------- critic-batched LayerNorm + ReLU (+ head) -----------------

template <bool HEAD>
__global__ __launch_bounds__(256) void ln_bc(const unsigned short* __restrict__ Xb,
                                             const float* __restrict__ gB,
                                             const float* __restrict__ btB,
                                             unsigned short* __restrict__ Yb,
                                             const float* __restrict__ WhB,
                                             const float* __restrict__ qtB,
                                             float* __restrict__ outB) {
  const int gb = blockIdx.x;
  const int c = gb >> 14;                 // BATCH = 2^14
  const int row = gb & (BATCH - 1);
  const unsigned short* X = Xb + ((size_t)c * BATCH + row) * HDIM;
  const float* g   = gB + c * HDIM;
  const float* bta = btB + c * HDIM;

  const int tid = threadIdx.x;
  const int lane = tid & 63;
  const int wave = tid >> 6;
  __shared__ float rs_[4], rq_[4], rp_[4];

  const ushort4 xv = ((const ushort4*)X)[tid];
  const float x0 = bf2f(xv.x), x1 = bf2f(xv.y), x2 = bf2f(xv.z), x3 = bf2f(xv.w);
  float s = x0 + x1 + x2 + x3;
  float q = x0 * x0 + x1 * x1 + x2 * x2 + x3 * x3;
  #pragma unroll
  for (int off = 32; off; off >>= 1) {
    s += __shfl_xor(s, off);
    q += __shfl_xor(q, off);
  }
  if (lane == 0) { rs_[wave] = s; rq_[wave] = q; }
  __syncthreads();
  s = rs_[0] + rs_[1] + rs_[2] + rs_[3];
  q = rq_[0] + rq_[1] + rq_[2] + rq_[3];
  const float mu = s * (1.0f / 1024.0f);
  const float var = q * (1.0f / 1024.0f) - mu * mu;
  const float rsig = rsqrtf(var + 1e-5f);

  const float4 gv = ((const float4*)g)[tid];
  const float4 bv = ((const float4*)bta)[tid];
  const float y0 = fmaxf((x0 - mu) * rsig * gv.x + bv.x, 0.0f);
  const float y1 = fmaxf((x1 - mu) * rsig * gv.y + bv.y, 0.0f);
  const float y2 = fmaxf((x2 - mu) * rsig * gv.z + bv.z, 0.0f);
  const float y3 = fmaxf((x3 - mu) * rsig * gv.w + bv.w, 0.0f);

  if constexpr (!HEAD) {
    ushort4 o;
    o.x = f2bf(y0); o.y = f2bf(y1); o.z = f2bf(y2); o.w = f2bf(y3);
    ((ushort4*)(Yb + ((size_t)c * BATCH + row) * HDIM))[tid] = o;
  } else {
    const float* Wh = WhB + c * (HDIM + QED);
    const float4 wv = ((const float4*)Wh)[tid];
    float p = y0 * wv.x + y1 * wv.y + y2 * wv.z + y3 * wv.w;
    #pragma unroll
    for (int off = 32; off; off >>= 1) p += __shfl_xor(p, off);
    if (lane == 0) rp_[wave] = p;
    __syncthreads();
    if (tid < 64) {
      const float qf = rp_[0] + rp_[1] + rp_[2] + rp_[3];
      outB[((size_t)c * BATCH + row) * NQD + tid] = qf + qtB[c * 64 + tid];
    }
  }
}

// ---------------- launch ----------------

extern "C" void kernel_launch(void* const* d_in, const int* in_sizes, int n_in,
                              void* d_out, int out_size, void* d_ws, size_t ws_size,
                              hipStream_t stream) {
  (void)in_sizes; (void)n_in; (void)out_size; (void)ws_size;
  const float* state  = (const float*)d_in[0];
  const float* action = (const float*)d_in[1];
  const float* We1 = (const float*)d_in[2];
  const float* be1 = (const float*)d_in[3];
  const float* We2 = (const float*)d_in[4];
  const float* be2 = (const float*)d_in[5];
  const float* Wf1 = (const float*)d_in[6];
  const float* bW1 = (const float*)d_in[7];
  const float* g1  = (const float*)d_in[8];
  const float* bt1 = (const float*)d_in[9];
  const float* Wf2 = (const float*)d_in[10];
  const float* bW2 = (const float*)d_in[11];
  const float* g2  = (const float*)d_in[12];
  const float* bt2 = (const float*)d_in[13];
  const float* Wh  = (const float*)d_in[14];
  const float* bh  = (const float*)d_in[15];
  float* out = (float*)d_out;

  char* ws = (char*)d_ws;
  unsigned short* xb   = (unsigned short*)(ws);               // BATCH*576 bf16   (18,874,368 B)
  unsigned short* w1b  = (unsigned short*)(ws + 18874368);    // 2*1024*576 bf16  (2,359,296 B)
  unsigned short* w2b  = (unsigned short*)(ws + 21233664);    // 2*1024*1024 bf16 (4,194,304 B)
  float*          qtw  = (float*)(ws + 25427968);             // 2*64 f32 (512 B)
  unsigned short* ha   = (unsigned short*)(ws + 25428480);    // 2*BATCH*1024 bf16 -> ends 92,537,344
  unsigned short* hb   = (unsigned short*)(ws + 92537344);    // 2*BATCH*1024 bf16 -> ends 159,646,208

  prep_all<<<2080, 256, 0, stream>>>(state, action, xb, Wf1, w1b, Wf2, w2b,
                                     We1, be1, We2, be2, Wh, bh, qtw);

  // layer 1, both critics (A shared across critics): ha = x @ W1^T + b1
  gemm_bc<XDIM><<<1024, 512, 0, stream>>>(xb, 0, w1b, bW1, ha);
  ln_bc<false><<<2 * BATCH, 256, 0, stream>>>(ha, g1, bt1, hb, nullptr, nullptr, nullptr);
  // layer 2, both critics: ha = hb @ W2^T + b2 ; then LN+head -> out
  gemm_bc<HDIM><<<1024, 512, 0, stream>>>(hb, (size_t)BATCH * HDIM, w2b, bW2, ha);
  ln_bc<true><<<2 * BATCH, 256, 0, stream>>>(ha, g2, bt2, nullptr, Wh, qtw, out);
}

// Round 19
// 190.227 us; speedup vs baseline: 1.0959x; 1.0316x over previous
//
#include <hip/hip_runtime.h>
#include <stdint.h>

#define BATCH 16384
#define SDIM 512
#define ADIM 64
#define XDIM 576      // SDIM + ADIM
#define HDIM 1024
#define NQD 64
#define QED 64

typedef __attribute__((ext_vector_type(8))) short short8;
typedef __attribute__((ext_vector_type(4))) float f32x4;

static __device__ inline unsigned short f2bf(float f) {
  unsigned int u = __float_as_uint(f);
  unsigned int r = (u + 0x7fffu + ((u >> 16) & 1u)) >> 16;
  return (unsigned short)r;
}
static __device__ inline float bf2f(unsigned short u) {
  return __uint_as_float(((unsigned int)u) << 16);
}

static __device__ inline void gload_lds16(const void* g, void* l) {
  __builtin_amdgcn_global_load_lds(
      (const __attribute__((address_space(1))) uint32_t*)g,
      (__attribute__((address_space(3))) uint32_t*)l, 16, 0, 0);
}

// ---------------- merged conversion + tau kernel ----------------
// blocks 0..2047: x concat + W_f1/W_f2 bf16 conversion (grid-stride)
// blocks 2048..2079: tau-embedding head contribution (4 units/block)

__global__ __launch_bounds__(256) void prep_all(const float* __restrict__ st,
                                                const float* __restrict__ ac,
                                                unsigned short* __restrict__ xb,
                                                const float* __restrict__ w1s,
                                                unsigned short* __restrict__ w1d,
                                                const float* __restrict__ w2s,
                                                unsigned short* __restrict__ w2d,
                                                const float* __restrict__ We1,
                                                const float* __restrict__ be1,
                                                const float* __restrict__ We2,
                                                const float* __restrict__ be2,
                                                const float* __restrict__ Wh,
                                                const float* __restrict__ bh,
                                                float* __restrict__ qtau) {
  const int bid = (int)blockIdx.x;
  if (bid >= 2048) {
    // ---- qtau part: exact fp32, one wave per (c, nq) unit ----
    const int u = (bid - 2048) * 4 + ((int)threadIdx.x >> 6);  // 0..127
    const int c = u >> 6;
    const int nq = u & 63;
    const int q = (int)threadIdx.x & 63;
    const float tau = (float)nq / 64.0f + 0.0078125f;
    float acc = be2[c * 64 + q];
    for (int e = 0; e < 64; ++e) {
      const float t1 = fmaxf(tau * We1[c * 64 + e] + be1[c * 64 + e], 0.0f);
      acc += t1 * We2[(c * 64 + q) * 64 + e];
    }
    float v = acc * Wh[c * (HDIM + QED) + HDIM + q];
    #pragma unroll
    for (int off = 32; off; off >>= 1) v += __shfl_xor(v, off);
    if (q == 0) qtau[c * 64 + nq] = v + bh[c];
    return;
  }
  const int nx = BATCH * XDIM / 4;
  const int n1 = 2 * HDIM * XDIM / 4;
  const int n2 = 2 * HDIM * HDIM / 4;
  for (int i = bid * 256 + (int)threadIdx.x; i < nx + n1 + n2; i += 2048 * 256) {
    float4 v;
    unsigned short* dst;
    int di;
    if (i < nx) {
      const int e = i * 4;
      const int b = e / XDIM;
      const int j = e - b * XDIM;
      if (j < SDIM) v = *(const float4*)(st + (size_t)b * SDIM + j);
      else          v = *(const float4*)(ac + (size_t)b * ADIM + (j - SDIM));
      dst = xb; di = i;
    } else if (i < nx + n1) {
      di = i - nx; v = ((const float4*)w1s)[di]; dst = w1d;
    } else {
      di = i - nx - n1; v = ((const float4*)w2s)[di]; dst = w2d;
    }
    ushort4 o;
    o.x = f2bf(v.x); o.y = f2bf(v.y); o.z = f2bf(v.z); o.w = f2bf(v.w);
    ((ushort4*)dst)[di] = o;
  }
}

// ---------------- critic-batched 256x128 bf16 GEMM (R12/R15, proven best) --
// Both critics in ONE dispatch (grid 1024). C[c][M,1024] = A[c] * W[c]^T + b[c].
// 8 waves (4M x 2N), BK=32, 48 KiB LDS dbuf, both-sides slot swizzle,
// packed LDS-transpose epilogue (full-128B-line dwordx4 stores).
// Block mapping keeps the 16 blocks (8n x 2c) sharing an A-panel XCD-co-resident.
// NOTE: A and C must NOT alias (in-dispatch cross-block RW race otherwise).

template <int K>
__global__ __launch_bounds__(512, 4) void gemm_bc(const unsigned short* __restrict__ Abase,
                                                  size_t aCritStride,
                                                  const unsigned short* __restrict__ Wbase,
                                                  const float* __restrict__ biasBase,
                                                  unsigned short* __restrict__ Cbase) {
  constexpr int NT = K / 32;
  __shared__ unsigned short As[2][256][32];  // 32 KiB
  __shared__ unsigned short Bs[2][128][32];  // 16 KiB  (48 KiB pool, reused by epilogue)

  const int tid  = threadIdx.x;
  const int lane = tid & 63;
  const int wave = tid >> 6;
  const int wm = wave >> 1;   // 0..3 -> rows [wm*64, wm*64+64)
  const int wn = wave & 1;    // 0..1 -> cols [wn*64, wn*64+64)

  const int bid = (int)blockIdx.x;
  const int L = (bid & 7) * 128 + (bid >> 3);
  const int n = L & 7;
  const int cidx = (L >> 3) & 1;
  const int m = L >> 4;
  const int mBase = m * 256;
  const int nBase = n * 128;

  const unsigned short* A = Abase + aCritStride * (size_t)cidx;
  const unsigned short* W = Wbase + (size_t)cidx * HDIM * K;
  const float* bias = biasBase + cidx * HDIM;
  unsigned short* C = Cbase + (size_t)cidx * BATCH * HDIM;

  auto stage = [&](int buf, int kt) {
    #pragma unroll
    for (int i = 0; i < 2; ++i) {
      const int flat = i * 512 + tid;
      const int row  = flat >> 2;
      const int ls   = (flat & 3) ^ ((row >> 1) & 3);
      gload_lds16(A + (size_t)(mBase + row) * K + kt * 32 + ls * 8,
                  &As[buf][0][0] + (size_t)flat * 8);
    }
    {
      const int row = tid >> 2;
      const int ls  = (tid & 3) ^ ((row >> 1) & 3);
      gload_lds16(W + (size_t)(nBase + row) * K + kt * 32 + ls * 8,
                  &Bs[buf][0][0] + (size_t)tid * 8);
    }
  };

  f32x4 acc[4][4];
  #pragma unroll
  for (int fm = 0; fm < 4; ++fm)
    #pragma unroll
    for (int fn = 0; fn < 4; ++fn) {
      f32x4 z = {0.f, 0.f, 0.f, 0.f};
      acc[fm][fn] = z;
    }

  stage(0, 0);
  __syncthreads();

  for (int t = 0; t < NT; ++t) {
    const int buf = t & 1;
    if (t + 1 < NT) stage(buf ^ 1, t + 1);

    short8 af[4], bf[4];
    #pragma unroll
    for (int fm = 0; fm < 4; ++fm) {
      const int r  = wm * 64 + fm * 16 + (lane & 15);
      const int ps = (lane >> 4) ^ ((r >> 1) & 3);
      af[fm] = *(const short8*)&As[buf][r][ps * 8];
    }
    #pragma unroll
    for (int fn = 0; fn < 4; ++fn) {
      const int r  = wn * 64 + fn * 16 + (lane & 15);
      const int ps = (lane >> 4) ^ ((r >> 1) & 3);
      bf[fn] = *(const short8*)&Bs[buf][r][ps * 8];
    }

    __builtin_amdgcn_s_setprio(1);
    #pragma unroll
    for (int fm = 0; fm < 4; ++fm)
      #pragma unroll
      for (int fn = 0; fn < 4; ++fn)
        acc[fm][fn] = __builtin_amdgcn_mfma_f32_16x16x32_bf16(af[fm], bf[fn],
                                                              acc[fm][fn], 0, 0, 0);
    __builtin_amdgcn_s_setprio(0);
    __syncthreads();
  }

  // ---- packed epilogue: LDS transpose -> full-128B-line dwordx4 stores ----
  __syncthreads();  // all waves done reading As/Bs before patch overwrite
  unsigned short* patch = ((unsigned short*)&As[0][0][0]) + wave * 2304;  // 32x72 shorts

  float bcol[4];
  #pragma unroll
  for (int fn = 0; fn < 4; ++fn)
    bcol[fn] = bias[nBase + wn * 64 + fn * 16 + (lane & 15)];

  const int cBase = nBase + wn * 64;

  #pragma unroll
  for (int p = 0; p < 2; ++p) {
    #pragma unroll
    for (int f2 = 0; f2 < 2; ++f2) {
      const int fm = p * 2 + f2;
      #pragma unroll
      for (int fn = 0; fn < 4; ++fn) {
        const int rl = f2 * 16 + (lane >> 4) * 4;
        const int cl = fn * 16 + (lane & 15);
        #pragma unroll
        for (int j = 0; j < 4; ++j)
          patch[(rl + j) * 72 + cl] = f2bf(acc[fm][fn][j] + bcol[fn]);
      }
    }
    #pragma unroll
    for (int k = 0; k < 4; ++k) {
      const int rl = k * 8 + (lane >> 3);
      const short8 v = *(const short8*)&patch[rl * 72 + (lane & 7) * 8];
      const int rowg = mBase + wm * 64 + p * 32 + rl;
      *(short8*)(C + (size_t)rowg * HDIM + cBase + (lane & 7) * 8) = v;
    }
  }
}

// ---------------- wave-per-row LayerNorm + ReLU (+ head), barrier-free -----
// 4 independent waves per block (grid 8192), one row per wave. Lane owns 16
// contiguous bf16 (32 B); stats via shfl_xor only — no LDS, no barriers.

template <bool HEAD>
__global__ __launch_bounds__(256) void ln_bc(const unsigned short* __restrict__ Xb,
                                             const float* __restrict__ gB,
                                             const float* __restrict__ btB,
                                             unsigned short* __restrict__ Yb,
                                             const float* __restrict__ WhB,
                                             const float* __restrict__ qtB,
                                             float* __restrict__ outB) {
  const int gr = (int)blockIdx.x * 4 + ((int)threadIdx.x >> 6);  // 0..2*BATCH-1
  const int c = gr >> 14;                                        // BATCH = 2^14
  const int lane = (int)threadIdx.x & 63;

  const unsigned short* X = Xb + (size_t)gr * HDIM + lane * 16;
  const float* g   = gB + c * HDIM + lane * 16;
  const float* bta = btB + c * HDIM + lane * 16;

  const short8 v0 = *(const short8*)(X);
  const short8 v1 = *(const short8*)(X + 8);
  float x[16];
  #pragma unroll
  for (int j = 0; j < 8; ++j) {
    x[j]     = bf2f((unsigned short)v0[j]);
    x[8 + j] = bf2f((unsigned short)v1[j]);
  }
  float s = 0.f, q = 0.f;
  #pragma unroll
  for (int j = 0; j < 16; ++j) { s += x[j]; q += x[j] * x[j]; }
  #pragma unroll
  for (int off = 32; off; off >>= 1) {
    s += __shfl_xor(s, off);
    q += __shfl_xor(q, off);
  }
  const float mu = s * (1.0f / 1024.0f);
  const float var = q * (1.0f / 1024.0f) - mu * mu;
  const float rsig = rsqrtf(var + 1e-5f);

  float y[16];
  #pragma unroll
  for (int j = 0; j < 16; j += 4) {
    const float4 gv = *(const float4*)(g + j);
    const float4 bv = *(const float4*)(bta + j);
    y[j]     = fmaxf((x[j]     - mu) * rsig * gv.x + bv.x, 0.0f);
    y[j + 1] = fmaxf((x[j + 1] - mu) * rsig * gv.y + bv.y, 0.0f);
    y[j + 2] = fmaxf((x[j + 2] - mu) * rsig * gv.z + bv.z, 0.0f);
    y[j + 3] = fmaxf((x[j + 3] - mu) * rsig * gv.w + bv.w, 0.0f);
  }

  if constexpr (!HEAD) {
    short8 o0, o1;
    #pragma unroll
    for (int j = 0; j < 8; ++j) {
      o0[j] = (short)f2bf(y[j]);
      o1[j] = (short)f2bf(y[8 + j]);
    }
    unsigned short* Y = Yb + (size_t)gr * HDIM + lane * 16;
    *(short8*)(Y)     = o0;
    *(short8*)(Y + 8) = o1;
  } else {
    const float* Wh = WhB + c * (HDIM + QED) + lane * 16;
    float p = 0.f;
    #pragma unroll
    for (int j = 0; j < 16; j += 4) {
      const float4 wv = *(const float4*)(Wh + j);
      p += y[j] * wv.x + y[j + 1] * wv.y + y[j + 2] * wv.z + y[j + 3] * wv.w;
    }
    #pragma unroll
    for (int off = 32; off; off >>= 1) p += __shfl_xor(p, off);
    outB[(size_t)gr * NQD + lane] = p + qtB[c * 64 + lane];
  }
}

// ---------------- launch ----------------

extern "C" void kernel_launch(void* const* d_in, const int* in_sizes, int n_in,
                              void* d_out, int out_size, void* d_ws, size_t ws_size,
                              hipStream_t stream) {
  (void)in_sizes; (void)n_in; (void)out_size; (void)ws_size;
  const float* state  = (const float*)d_in[0];
  const float* action = (const float*)d_in[1];
  const float* We1 = (const float*)d_in[2];
  const float* be1 = (const float*)d_in[3];
  const float* We2 = (const float*)d_in[4];
  const float* be2 = (const float*)d_in[5];
  const float* Wf1 = (const float*)d_in[6];
  const float* bW1 = (const float*)d_in[7];
  const float* g1  = (const float*)d_in[8];
  const float* bt1 = (const float*)d_in[9];
  const float* Wf2 = (const float*)d_in[10];
  const float* bW2 = (const float*)d_in[11];
  const float* g2  = (const float*)d_in[12];
  const float* bt2 = (const float*)d_in[13];
  const float* Wh  = (const float*)d_in[14];
  const float* bh  = (const float*)d_in[15];
  float* out = (float*)d_out;

  char* ws = (char*)d_ws;
  unsigned short* xb   = (unsigned short*)(ws);               // BATCH*576 bf16   (18,874,368 B)
  unsigned short* w1b  = (unsigned short*)(ws + 18874368);    // 2*1024*576 bf16  (2,359,296 B)
  unsigned short* w2b  = (unsigned short*)(ws + 21233664);    // 2*1024*1024 bf16 (4,194,304 B)
  float*          qtw  = (float*)(ws + 25427968);             // 2*64 f32 (512 B)
  unsigned short* ha   = (unsigned short*)(ws + 25428480);    // 2*BATCH*1024 bf16 -> ends 92,537,344
  unsigned short* hb   = (unsigned short*)(ws + 92537344);    // 2*BATCH*1024 bf16 -> ends 159,646,208

  prep_all<<<2080, 256, 0, stream>>>(state, action, xb, Wf1, w1b, Wf2, w2b,
                                     We1, be1, We2, be2, Wh, bh, qtw);

  // layer 1, both critics (A shared across critics): ha = x @ W1^T + b1
  gemm_bc<XDIM><<<1024, 512, 0, stream>>>(xb, 0, w1b, bW1, ha);
  ln_bc<false><<<2 * BATCH / 4, 256, 0, stream>>>(ha, g1, bt1, hb, nullptr, nullptr, nullptr);
  // layer 2, both critics: ha = hb @ W2^T + b2 ; then LN+head -> out
  gemm_bc<HDIM><<<1024, 512, 0, stream>>>(hb, (size_t)BATCH * HDIM, w2b, bW2, ha);
  ln_bc<true><<<2 * BATCH / 4, 256, 0, stream>>>(ha, g2, bt2, nullptr, Wh, qtw, out);
}

// Round 20
// 187.330 us; speedup vs baseline: 1.1129x; 1.0155x over previous
//
#include <hip/hip_runtime.h>
#include <stdint.h>

#define BATCH 16384
#define SDIM 512
#define ADIM 64
#define XDIM 576      // SDIM + ADIM
#define HDIM 1024
#define NQD 64
#define QED 64

typedef __attribute__((ext_vector_type(8))) short short8;
typedef __attribute__((ext_vector_type(4))) float f32x4;

static __device__ inline unsigned short f2bf(float f) {
  unsigned int u = __float_as_uint(f);
  unsigned int r = (u + 0x7fffu + ((u >> 16) & 1u)) >> 16;
  return (unsigned short)r;
}
static __device__ inline float bf2f(unsigned short u) {
  return __uint_as_float(((unsigned int)u) << 16);
}

static __device__ inline void gload_lds16(const void* g, void* l) {
  __builtin_amdgcn_global_load_lds(
      (const __attribute__((address_space(1))) uint32_t*)g,
      (__attribute__((address_space(3))) uint32_t*)l, 16, 0, 0);
}

#define FENCE() asm volatile("" ::: "memory")

// ---------------- merged conversion + tau kernel ----------------
// blocks 0..2047: x concat + W_f1/W_f2 bf16 conversion (grid-stride)
// blocks 2048..2079: tau-embedding head contribution (4 units/block)

__global__ __launch_bounds__(256) void prep_all(const float* __restrict__ st,
                                                const float* __restrict__ ac,
                                                unsigned short* __restrict__ xb,
                                                const float* __restrict__ w1s,
                                                unsigned short* __restrict__ w1d,
                                                const float* __restrict__ w2s,
                                                unsigned short* __restrict__ w2d,
                                                const float* __restrict__ We1,
                                                const float* __restrict__ be1,
                                                const float* __restrict__ We2,
                                                const float* __restrict__ be2,
                                                const float* __restrict__ Wh,
                                                const float* __restrict__ bh,
                                                float* __restrict__ qtau) {
  const int bid = (int)blockIdx.x;
  if (bid >= 2048) {
    // ---- qtau part: exact fp32, one wave per (c, nq) unit ----
    const int u = (bid - 2048) * 4 + ((int)threadIdx.x >> 6);  // 0..127
    const int c = u >> 6;
    const int nq = u & 63;
    const int q = (int)threadIdx.x & 63;
    const float tau = (float)nq / 64.0f + 0.0078125f;
    float acc = be2[c * 64 + q];
    for (int e = 0; e < 64; ++e) {
      const float t1 = fmaxf(tau * We1[c * 64 + e] + be1[c * 64 + e], 0.0f);
      acc += t1 * We2[(c * 64 + q) * 64 + e];
    }
    float v = acc * Wh[c * (HDIM + QED) + HDIM + q];
    #pragma unroll
    for (int off = 32; off; off >>= 1) v += __shfl_xor(v, off);
    if (q == 0) qtau[c * 64 + nq] = v + bh[c];
    return;
  }
  const int nx = BATCH * XDIM / 4;
  const int n1 = 2 * HDIM * XDIM / 4;
  const int n2 = 2 * HDIM * HDIM / 4;
  for (int i = bid * 256 + (int)threadIdx.x; i < nx + n1 + n2; i += 2048 * 256) {
    float4 v;
    unsigned short* dst;
    int di;
    if (i < nx) {
      const int e = i * 4;
      const int b = e / XDIM;
      const int j = e - b * XDIM;
      if (j < SDIM) v = *(const float4*)(st + (size_t)b * SDIM + j);
      else          v = *(const float4*)(ac + (size_t)b * ADIM + (j - SDIM));
      dst = xb; di = i;
    } else if (i < nx + n1) {
      di = i - nx; v = ((const float4*)w1s)[di]; dst = w1d;
    } else {
      di = i - nx - n1; v = ((const float4*)w2s)[di]; dst = w2d;
    }
    ushort4 o;
    o.x = f2bf(v.x); o.y = f2bf(v.y); o.z = f2bf(v.z); o.w = f2bf(v.w);
    ((ushort4*)dst)[di] = o;
  }
}

// ---------------- critic-batched 256x128 bf16 GEMM, ring-3 counted-vmcnt ---
// Both critics in ONE dispatch (grid 1024). C[c][M,1024] = A[c] * W[c]^T + b[c].
// 8 waves (4M x 2N), BK=32. NEW vs R19: 3 LDS ring buffers (72 KiB — still
// 2 blocks/CU, the VGPR cap) with 2-tiles-ahead prefetch and counted
// s_waitcnt vmcnt(3) at each step (never 0 mid-loop). Each stage() = exactly
// 3 gloads/thread, so vmcnt(3) drains precisely tile t+1 while t+2 stays in
// flight — removes the per-step full-latency vmcnt(0) drain of __syncthreads.
// Ring safety: step t stages slot (t+2)%3 = (t-1)%3, whose reads completed
// before the end-of-step-(t-1) barrier. Packed LDS-transpose epilogue after
// a vmcnt(0) barrier. NOTE: A and C must NOT alias.

template <int K>
__global__ __launch_bounds__(512, 4) void gemm_bc(const unsigned short* __restrict__ Abase,
                                                  size_t aCritStride,
                                                  const unsigned short* __restrict__ Wbase,
                                                  const float* __restrict__ biasBase,
                                                  unsigned short* __restrict__ Cbase) {
  constexpr int NT = K / 32;
  __shared__ unsigned short As[3][256][32];  // 48 KiB
  __shared__ unsigned short Bs[3][128][32];  // 24 KiB  (72 KiB pool, reused by epilogue)

  const int tid  = threadIdx.x;
  const int lane = tid & 63;
  const int wave = tid >> 6;
  const int wm = wave >> 1;   // 0..3 -> rows [wm*64, wm*64+64)
  const int wn = wave & 1;    // 0..1 -> cols [wn*64, wn*64+64)

  const int bid = (int)blockIdx.x;
  const int L = (bid & 7) * 128 + (bid >> 3);
  const int n = L & 7;
  const int cidx = (L >> 3) & 1;
  const int m = L >> 4;
  const int mBase = m * 256;
  const int nBase = n * 128;

  const unsigned short* A = Abase + aCritStride * (size_t)cidx;
  const unsigned short* W = Wbase + (size_t)cidx * HDIM * K;
  const float* bias = biasBase + cidx * HDIM;
  unsigned short* C = Cbase + (size_t)cidx * BATCH * HDIM;

  auto stage = [&](int ring, int kt) {
    #pragma unroll
    for (int i = 0; i < 2; ++i) {
      const int flat = i * 512 + tid;
      const int row  = flat >> 2;
      const int ls   = (flat & 3) ^ ((row >> 1) & 3);
      gload_lds16(A + (size_t)(mBase + row) * K + kt * 32 + ls * 8,
                  &As[ring][0][0] + (size_t)flat * 8);
    }
    {
      const int row = tid >> 2;
      const int ls  = (tid & 3) ^ ((row >> 1) & 3);
      gload_lds16(W + (size_t)(nBase + row) * K + kt * 32 + ls * 8,
                  &Bs[ring][0][0] + (size_t)tid * 8);
    }
  };

  f32x4 acc[4][4];
  #pragma unroll
  for (int fm = 0; fm < 4; ++fm)
    #pragma unroll
    for (int fn = 0; fn < 4; ++fn) {
      f32x4 z = {0.f, 0.f, 0.f, 0.f};
      acc[fm][fn] = z;
    }

  // prologue: stage tiles 0,1 (6 loads/thread); drain tile0 only (vmcnt 3)
  stage(0, 0);
  if (NT > 1) stage(1, 1);
  FENCE();
  if (NT > 1) asm volatile("s_waitcnt vmcnt(3)" ::: "memory");
  else        asm volatile("s_waitcnt vmcnt(0)" ::: "memory");
  __builtin_amdgcn_s_barrier();
  FENCE();

  for (int t = 0; t < NT; ++t) {
    const int rt = t % 3;
    if (t + 2 < NT) stage((t + 2) % 3, t + 2);

    short8 af[4], bf[4];
    #pragma unroll
    for (int fm = 0; fm < 4; ++fm) {
      const int r  = wm * 64 + fm * 16 + (lane & 15);
      const int ps = (lane >> 4) ^ ((r >> 1) & 3);
      af[fm] = *(const short8*)&As[rt][r][ps * 8];
    }
    #pragma unroll
    for (int fn = 0; fn < 4; ++fn) {
      const int r  = wn * 64 + fn * 16 + (lane & 15);
      const int ps = (lane >> 4) ^ ((r >> 1) & 3);
      bf[fn] = *(const short8*)&Bs[rt][r][ps * 8];
    }

    __builtin_amdgcn_s_setprio(1);
    #pragma unroll
    for (int fm = 0; fm < 4; ++fm)
      #pragma unroll
      for (int fn = 0; fn < 4; ++fn)
        acc[fm][fn] = __builtin_amdgcn_mfma_f32_16x16x32_bf16(af[fm], bf[fn],
                                                              acc[fm][fn], 0, 0, 0);
    __builtin_amdgcn_s_setprio(0);

    if (t + 1 < NT) {
      FENCE();
      if (t + 2 < NT) asm volatile("s_waitcnt vmcnt(3)" ::: "memory");
      else            asm volatile("s_waitcnt vmcnt(0)" ::: "memory");
      __builtin_amdgcn_s_barrier();
      FENCE();
    }
  }

  // ---- packed epilogue: LDS transpose -> full-128B-line dwordx4 stores ----
  FENCE();
  asm volatile("s_waitcnt vmcnt(0)" ::: "memory");
  __builtin_amdgcn_s_barrier();  // all waves done reading rings before patch overwrite
  FENCE();
  unsigned short* patch = ((unsigned short*)&As[0][0][0]) + wave * 2304;  // 32x72 shorts

  float bcol[4];
  #pragma unroll
  for (int fn = 0; fn < 4; ++fn)
    bcol[fn] = bias[nBase + wn * 64 + fn * 16 + (lane & 15)];

  const int cBase = nBase + wn * 64;

  #pragma unroll
  for (int p = 0; p < 2; ++p) {
    #pragma unroll
    for (int f2 = 0; f2 < 2; ++f2) {
      const int fm = p * 2 + f2;
      #pragma unroll
      for (int fn = 0; fn < 4; ++fn) {
        const int rl = f2 * 16 + (lane >> 4) * 4;
        const int cl = fn * 16 + (lane & 15);
        #pragma unroll
        for (int j = 0; j < 4; ++j)
          patch[(rl + j) * 72 + cl] = f2bf(acc[fm][fn][j] + bcol[fn]);
      }
    }
    #pragma unroll
    for (int k = 0; k < 4; ++k) {
      const int rl = k * 8 + (lane >> 3);
      const short8 v = *(const short8*)&patch[rl * 72 + (lane & 7) * 8];
      const int rowg = mBase + wm * 64 + p * 32 + rl;
      *(short8*)(C + (size_t)rowg * HDIM + cBase + (lane & 7) * 8) = v;
    }
  }
}

// ---------------- wave-per-row LayerNorm + ReLU (+ head), barrier-free -----
// 4 independent waves per block (grid 8192), one row per wave. Lane owns 16
// contiguous bf16 (32 B); stats via shfl_xor only — no LDS, no barriers.

template <bool HEAD>
__global__ __launch_bounds__(256) void ln_bc(const unsigned short* __restrict__ Xb,
                                             const float* __restrict__ gB,
                                             const float* __restrict__ btB,
                                             unsigned short* __restrict__ Yb,
                                             const float* __restrict__ WhB,
                                             const float* __restrict__ qtB,
                                             float* __restrict__ outB) {
  const int gr = (int)blockIdx.x * 4 + ((int)threadIdx.x >> 6);  // 0..2*BATCH-1
  const int c = gr >> 14;                                        // BATCH = 2^14
  const int lane = (int)threadIdx.x & 63;

  const unsigned short* X = Xb + (size_t)gr * HDIM + lane * 16;
  const float* g   = gB + c * HDIM + lane * 16;
  const float* bta = btB + c * HDIM + lane * 16;

  const short8 v0 = *(const short8*)(X);
  const short8 v1 = *(const short8*)(X + 8);
  float x[16];
  #pragma unroll
  for (int j = 0; j < 8; ++j) {
    x[j]     = bf2f((unsigned short)v0[j]);
    x[8 + j] = bf2f((unsigned short)v1[j]);
  }
  float s = 0.f, q = 0.f;
  #pragma unroll
  for (int j = 0; j < 16; ++j) { s += x[j]; q += x[j] * x[j]; }
  #pragma unroll
  for (int off = 32; off; off >>= 1) {
    s += __shfl_xor(s, off);
    q += __shfl_xor(q, off);
  }
  const float mu = s * (1.0f / 1024.0f);
  const float var = q * (1.0f / 1024.0f) - mu * mu;
  const float rsig = rsqrtf(var + 1e-5f);

  float y[16];
  #pragma unroll
  for (int j = 0; j < 16; j += 4) {
    const float4 gv = *(const float4*)(g + j);
    const float4 bv = *(const float4*)(bta + j);
    y[j]     = fmaxf((x[j]     - mu) * rsig * gv.x + bv.x, 0.0f);
    y[j + 1] = fmaxf((x[j + 1] - mu) * rsig * gv.y + bv.y, 0.0f);
    y[j + 2] = fmaxf((x[j + 2] - mu) * rsig * gv.z + bv.z, 0.0f);
    y[j + 3] = fmaxf((x[j + 3] - mu) * rsig * gv.w + bv.w, 0.0f);
  }

  if constexpr (!HEAD) {
    short8 o0, o1;
    #pragma unroll
    for (int j = 0; j < 8; ++j) {
      o0[j] = (short)f2bf(y[j]);
      o1[j] = (short)f2bf(y[8 + j]);
    }
    unsigned short* Y = Yb + (size_t)gr * HDIM + lane * 16;
    *(short8*)(Y)     = o0;
    *(short8*)(Y + 8) = o1;
  } else {
    const float* Wh = WhB + c * (HDIM + QED) + lane * 16;
    float p = 0.f;
    #pragma unroll
    for (int j = 0; j < 16; j += 4) {
      const float4 wv = *(const float4*)(Wh + j);
      p += y[j] * wv.x + y[j + 1] * wv.y + y[j + 2] * wv.z + y[j + 3] * wv.w;
    }
    #pragma unroll
    for (int off = 32; off; off >>= 1) p += __shfl_xor(p, off);
    outB[(size_t)gr * NQD + lane] = p + qtB[c * 64 + lane];
  }
}

// ---------------- launch ----------------

extern "C" void kernel_launch(void* const* d_in, const int* in_sizes, int n_in,
                              void* d_out, int out_size, void* d_ws, size_t ws_size,
                              hipStream_t stream) {
  (void)in_sizes; (void)n_in; (void)out_size; (void)ws_size;
  const float* state  = (const float*)d_in[0];
  const float* action = (const float*)d_in[1];
  const float* We1 = (const float*)d_in[2];
  const float* be1 = (const float*)d_in[3];
  const float* We2 = (const float*)d_in[4];
  const float* be2 = (const float*)d_in[5];
  const float* Wf1 = (const float*)d_in[6];
  const float* bW1 = (const float*)d_in[7];
  const float* g1  = (const float*)d_in[8];
  const float* bt1 = (const float*)d_in[9];
  const float* Wf2 = (const float*)d_in[10];
  const float* bW2 = (const float*)d_in[11];
  const float* g2  = (const float*)d_in[12];
  const float* bt2 = (const float*)d_in[13];
  const float* Wh  = (const float*)d_in[14];
  const float* bh  = (const float*)d_in[15];
  float* out = (float*)d_out;

  char* ws = (char*)d_ws;
  unsigned short* xb   = (unsigned short*)(ws);               // BATCH*576 bf16   (18,874,368 B)
  unsigned short* w1b  = (unsigned short*)(ws + 18874368);    // 2*1024*576 bf16  (2,359,296 B)
  unsigned short* w2b  = (unsigned short*)(ws + 21233664);    // 2*1024*1024 bf16 (4,194,304 B)
  float*          qtw  = (float*)(ws + 25427968);             // 2*64 f32 (512 B)
  unsigned short* ha   = (unsigned short*)(ws + 25428480);    // 2*BATCH*1024 bf16 -> ends 92,537,344
  unsigned short* hb   = (unsigned short*)(ws + 92537344);    // 2*BATCH*1024 bf16 -> ends 159,646,208

  prep_all<<<2080, 256, 0, stream>>>(state, action, xb, Wf1, w1b, Wf2, w2b,
                                     We1, be1, We2, be2, Wh, bh, qtw);

  // layer 1, both critics (A shared across critics): ha = x @ W1^T + b1
  gemm_bc<XDIM><<<1024, 512, 0, stream>>>(xb, 0, w1b, bW1, ha);
  ln_bc<false><<<2 * BATCH / 4, 256, 0, stream>>>(ha, g1, bt1, hb, nullptr, nullptr, nullptr);
  // layer 2, both critics: ha = hb @ W2^T + b2 ; then LN+head -> out
  gemm_bc<HDIM><<<1024, 512, 0, stream>>>(hb, (size_t)BATCH * HDIM, w2b, bW2, ha);
  ln_bc<true><<<2 * BATCH / 4, 256, 0, stream>>>(ha, g2, bt2, nullptr, Wh, qtw, out);
}